// Round 10
// baseline (105.665 us; speedup 1.0000x reference)
//
#include <hip/hip_runtime.h>

// Batched 3x3 expm(T) @ x, T = sum_m c[b,m]*psi[m]. Scalar Cayley-Hamilton
// pipeline, one batch per thread. FINAL (measured-best, R6/R8 structure):
//  (1) exp(A) = b0 I + b1 A + b2 A^2 (A = T/4) via Horner in the quotient
//      ring: h <- h*lam + 1/k!, h=(b0,b1,b2) reduced mod char-poly on the
//      fly — 3 FMA/order.
//  (2) two squarings in coefficient space (poly-square mod char-poly,
//      15 ops each; the matrix E is never formed).
//  (3) tail y = b0 x + (b1/4) Tx + (b2/16) T(Tx).
// ~132 core FMA/thread. Falsified alternatives (keep for posterity):
//  - 2 or 4 batches/thread: VGPR>64 halves wave pool -> regressed (R4,R7)
//  - LDS-staged perfectly-coalesced I/O: barriers+LDS ops cost more than
//    scattered VMEM saves (R5)
//  - __constant__ psi: neutral (psi reads already uniform s_loads) (R7)
//  - v_pk_fma_f32 T-build, dwordx4 c-load, nontemporal stores: neutral
//    to slightly negative (R9)
__global__ __launch_bounds__(256) void expm_kernel(
    const float* __restrict__ x,
    const float* __restrict__ c,
    const float* __restrict__ psi,
    float* __restrict__ out)
{
    const int b = blockIdx.x * blockDim.x + threadIdx.x;  // B = 2^21 exact

    // ---- c[b,0:6] as 3x float2 (24 B/batch, 8B aligned) ----
    const float2* c2 = reinterpret_cast<const float2*>(c + (size_t)b * 6);
    const float2 ca = c2[0], cb = c2[1], cc = c2[2];
    const float cm[6] = {ca.x, ca.y, cb.x, cb.y, cc.x, cc.y};

    // ---- T = sum_m c[m] * psi[m]  (psi uniform -> scalarized s_loads) ----
    float T[9];
#pragma unroll
    for (int j = 0; j < 9; ++j) {
        float s = cm[0] * psi[0 * 9 + j];
#pragma unroll
        for (int m = 1; m < 6; ++m) s = fmaf(cm[m], psi[m * 9 + j], s);
        T[j] = s;
    }

    // ---- invariants of T, scaled to A = T/4:
    //      char poly: lam^3 = c2v lam^2 + c1v lam + c0v ----
    const float trT = T[0] + T[4] + T[8];
    const float m01 = fmaf(T[0], T[4], -T[1] * T[3]);
    const float m02 = fmaf(T[0], T[8], -T[2] * T[6]);
    const float m12 = fmaf(T[4], T[8], -T[5] * T[7]);
    const float msT = m01 + m02 + m12;
    const float M10 = fmaf(T[3], T[8], -T[5] * T[6]);
    const float M20 = fmaf(T[3], T[7], -T[4] * T[6]);
    const float detT = fmaf(T[0], m12, fmaf(-T[1], M10, T[2] * M20));
    const float c2v = trT * 0.25f;       // tr(A)
    const float c1v = msT * -0.0625f;    // -(sum principal minors of A)
    const float c0v = detT * 0.015625f;  // det(A)

    // lam^4 fold-back (shared by both squarings)
    const float d2 = fmaf(c2v, c2v, c1v);
    const float d1 = fmaf(c2v, c1v, c0v);
    const float d0 = c2v * c0v;

    // ---- order-8 Taylor, Horner in the quotient ring ----
    // h = 1/8!; for k=7..0: h = h*lam mod m + 1/k!
    const float tk[8] = {1.0f,            // 1/0!
                         1.0f,            // 1/1!
                         0.5f,            // 1/2!
                         1.6666667e-1f,   // 1/3!
                         4.1666667e-2f,   // 1/4!
                         8.3333333e-3f,   // 1/5!
                         1.3888889e-3f,   // 1/6!
                         1.9841270e-4f};  // 1/7!
    float b0 = 2.4801587e-5f, b1 = 0.0f, b2 = 0.0f;  // h = 1/8!
#pragma unroll
    for (int k = 7; k >= 0; --k) {
        const float n0 = fmaf(b2, c0v, tk[k]);  // tk const after unroll
        const float n1 = fmaf(b2, c1v, b0);
        const float n2 = fmaf(b2, c2v, b1);
        b0 = n0; b1 = n1; b2 = n2;
    }

    // ---- two squarings in coefficient space: b <- b^2 mod m ----
#pragma unroll
    for (int s2 = 0; s2 < 2; ++s2) {
        const float q0 = b0 * b0;
        const float q1 = 2.0f * (b0 * b1);
        const float q2 = fmaf(b1, b1, 2.0f * (b0 * b2));
        const float q3 = 2.0f * (b1 * b2);
        const float q4 = b2 * b2;
        b0 = fmaf(d0, q4, fmaf(c0v, q3, q0));
        b1 = fmaf(d1, q4, fmaf(c1v, q3, q1));
        b2 = fmaf(d2, q4, fmaf(c2v, q3, q2));
    }
    // exp(T) = b0 I + b1 A + b2 A^2,  A = T/4
    const float b1q = b1 * 0.25f;
    const float b2q = b2 * 0.0625f;

    // ---- y = b0 x + b1q (Tx) + b2q T(Tx) ----
    const float* xb = x + (size_t)b * 3;
    const float x0 = xb[0], x1 = xb[1], x2 = xb[2];
    const float w0 = fmaf(T[0], x0, fmaf(T[1], x1, T[2] * x2));
    const float w1 = fmaf(T[3], x0, fmaf(T[4], x1, T[5] * x2));
    const float w2 = fmaf(T[6], x0, fmaf(T[7], x1, T[8] * x2));
    const float v0 = fmaf(T[0], w0, fmaf(T[1], w1, T[2] * w2));
    const float v1 = fmaf(T[3], w0, fmaf(T[4], w1, T[5] * w2));
    const float v2 = fmaf(T[6], w0, fmaf(T[7], w1, T[8] * w2));

    float* ob = out + (size_t)b * 3;
    ob[0] = fmaf(b0, x0, fmaf(b1q, w0, b2q * v0));
    ob[1] = fmaf(b0, x1, fmaf(b1q, w1, b2q * v1));
    ob[2] = fmaf(b0, x2, fmaf(b1q, w2, b2q * v2));
}

extern "C" void kernel_launch(void* const* d_in, const int* in_sizes, int n_in,
                              void* d_out, int out_size, void* d_ws, size_t ws_size,
                              hipStream_t stream) {
    const float* x   = (const float*)d_in[0];  // [B,3,1]
    const float* c   = (const float*)d_in[1];  // [B,6]
    const float* psi = (const float*)d_in[2];  // [6,3,3]
    float* out = (float*)d_out;                // [B,3,1]

    const int B = in_sizes[1] / 6;  // 2097152 = 2^21, divisible by 256
    const int block = 256;
    const int grid = B / block;
    expm_kernel<<<grid, block, 0, stream>>>(x, c, psi, out);
}